// Round 19
// baseline (161.513 us; speedup 1.0000x reference)
//
#include <hip/hip_runtime.h>
#include <hip/hip_bf16.h>
#include <stdint.h>

// MixAttention: B=4, L=2048, D=512, H=8, A=64
// ws layout (bytes):
//  wt   @ 0        : 6*512*512*2   = 3145728   (W^T bf16, [mat][out][in])
//  qws  @ 3145728  : 32*2048*128*2 = 16777216  (Q' = [qd|qt]*0.125*log2e, [bh][l][128])
//  kws  @ 19922944 : 16777216                  (K' = [kd|kt], [bh][l][128])
//  vws  @ 36700160 : 32*64*2048*2  = 8388608   (V^T, [bh][a][l'], l' pi-permuted in 64-blocks)
//  ctxb @ 45088768 : 8192*512*2    = 8388608   (attn out, [row][512])

using f32x4  = __attribute__((ext_vector_type(4))) float;
using bf16x8 = __attribute__((ext_vector_type(8))) short;

typedef __attribute__((address_space(1))) const uint32_t g_u32;
typedef __attribute__((address_space(3))) uint32_t l_u32;

#if __has_builtin(__builtin_amdgcn_exp2f)
#define EXP2F __builtin_amdgcn_exp2f
#else
#define EXP2F exp2f
#endif
#define QSCALE 0.1803368801111204f  /* 0.125 * log2(e): scores in log2 units */

__device__ __forceinline__ void glds16(const void* g, void* l) {
  __builtin_amdgcn_global_load_lds((g_u32*)g, (l_u32*)l, 16, 0, 0);
}

__device__ __forceinline__ unsigned short f2bfu(float f) {
  __hip_bfloat16 h = __float2bfloat16(f);
  union { __hip_bfloat16 h; unsigned short u; } v;
  v.h = h;
  return v.u;
}

// pack two non-negative finite floats to 2xbf16 by truncation (1 v_perm_b32)
__device__ __forceinline__ uint32_t pack_trunc(float lo, float hi) {
  union { float f; uint32_t u; } a, b;
  a.f = lo; b.f = hi;
  return __builtin_amdgcn_perm(b.u, a.u, 0x07060302u);
}

// ---------------- K0a: W [512 in][512 out] f32 -> W^T [out][in] bf16 ----------------
__global__ __launch_bounds__(256) void k_prep_w(
    const float* __restrict__ w0, const float* __restrict__ w1,
    const float* __restrict__ w2, const float* __restrict__ w3,
    const float* __restrict__ w4, const float* __restrict__ w5,
    unsigned short* __restrict__ wt) {
  __shared__ float tile[64][68];
  const float* wsrc[6] = {w0, w1, w2, w3, w4, w5};
  int bid = blockIdx.x;
  int mat = bid >> 6, tid = bid & 63;
  int k0 = (tid >> 3) << 6, c0 = (tid & 7) << 6;
  const float* w = wsrc[mat];
  int t = threadIdx.x;
  {
    int r = t >> 2, cq = (t & 3) << 4;
    const float4* src = reinterpret_cast<const float4*>(w + (size_t)(k0 + r) * 512 + c0 + cq);
#pragma unroll
    for (int j = 0; j < 4; ++j) {
      float4 v = src[j];
      tile[r][cq + j * 4 + 0] = v.x;
      tile[r][cq + j * 4 + 1] = v.y;
      tile[r][cq + j * 4 + 2] = v.z;
      tile[r][cq + j * 4 + 3] = v.w;
    }
  }
  __syncthreads();
  {
    int cc = t >> 2, kq = (t & 3) << 4;
    union { unsigned short u[16]; uint4 v[2]; } p;
#pragma unroll
    for (int j = 0; j < 16; ++j) p.u[j] = f2bfu(tile[kq + j][cc]);
    unsigned short* dst = wt + (size_t)mat * 262144 + (size_t)(c0 + cc) * 512 + k0 + kq;
    *reinterpret_cast<uint4*>(dst)     = p.v[0];
    *reinterpret_cast<uint4*>(dst + 8) = p.v[1];
  }
}

// ---- K1: 5 projections, 128x128 tile, 8 waves; A reg-prefetch + B glds16 dbuf.
//      Coalesced epilogue via LDS round-trip. (R18 verbatim)
__global__ __launch_bounds__(512) void k_proj2(
    const float* __restrict__ x0, const float* __restrict__ x1,
    const float* __restrict__ x2, const float* __restrict__ x3,
    const float* __restrict__ x4,
    const unsigned short* __restrict__ wt,
    const float* __restrict__ b0, const float* __restrict__ b1,
    const float* __restrict__ b2, const float* __restrict__ b3,
    const float* __restrict__ b4,
    unsigned short* __restrict__ qws, unsigned short* __restrict__ kws,
    unsigned short* __restrict__ vws) {
  __shared__ __align__(16) unsigned short plds[24576];  // Abuf[8192] | Bbuf0[8192] | Bbuf1[8192]
  int bid = blockIdx.x;
  int proj = bid >> 8, rem = bid & 255;
  int cb = rem >> 6, rb = rem & 63;
  const float* xs[5] = {x0, x1, x2, x3, x4};
  const float* Ag = xs[proj] + (size_t)rb * 128 * 512;
  const unsigned short* Wg = wt + (size_t)proj * 262144 + (size_t)cb * 128 * 512;
  int t = threadIdx.x;
  int lane = t & 63, w = t >> 6, wr = w >> 2, wc = w & 3, g = lane >> 4, c = lane & 15;
  f32x4 acc[4][2];
#pragma unroll
  for (int i = 0; i < 4; ++i)
#pragma unroll
    for (int j = 0; j < 2; ++j) acc[i][j] = f32x4{0.f, 0.f, 0.f, 0.f};

  int srow[2], sch[2];
#pragma unroll
  for (int j = 0; j < 2; ++j) {
    int q = t + j * 512;
    srow[j] = q >> 3;
    sch[j] = q & 7;
  }
  float4 pa[2], pb[2];
#pragma unroll
  for (int j = 0; j < 2; ++j) {
    const float* src = Ag + (size_t)srow[j] * 512 + sch[j] * 8;
    pa[j] = *reinterpret_cast<const float4*>(src);
    pb[j] = *reinterpret_cast<const float4*>(src + 4);
  }
#pragma unroll
  for (int j = 0; j < 2; ++j) {
    int cid = t + j * 512;
    int row = cid >> 3, ch = cid & 7;
    glds16(Wg + (size_t)row * 512 + ((ch ^ (row & 7)) << 3),
           plds + 8192 + cid * 8);
  }

#pragma unroll 1
  for (int it = 0; it < 8; ++it) {
    int cur = it & 1;
    unsigned short* Bcur = plds + 8192 + cur * 8192;
    unsigned short* Bnxt = plds + 8192 + (cur ^ 1) * 8192;
    __syncthreads();  // drains A-regs + B(it) glds16 (issued a full compute-phase ago)
#pragma unroll
    for (int j = 0; j < 2; ++j) {
      union { unsigned short u[8]; uint4 v; } p;
      p.u[0] = f2bfu(pa[j].x); p.u[1] = f2bfu(pa[j].y);
      p.u[2] = f2bfu(pa[j].z); p.u[3] = f2bfu(pa[j].w);
      p.u[4] = f2bfu(pb[j].x); p.u[5] = f2bfu(pb[j].y);
      p.u[6] = f2bfu(pb[j].z); p.u[7] = f2bfu(pb[j].w);
      *reinterpret_cast<uint4*>(&plds[srow[j] * 64 + ((sch[j] ^ (srow[j] & 7)) << 3)]) = p.v;
    }
    __syncthreads();  // drains only lgkm (A ds_write) -- cheap
    if (it < 7) {
#pragma unroll
      for (int j = 0; j < 2; ++j) {
        const float* src = Ag + (size_t)srow[j] * 512 + (it + 1) * 64 + sch[j] * 8;
        pa[j] = *reinterpret_cast<const float4*>(src);
        pb[j] = *reinterpret_cast<const float4*>(src + 4);
      }
#pragma unroll
      for (int j = 0; j < 2; ++j) {
        int cid = t + j * 512;
        int row = cid >> 3, ch = cid & 7;
        glds16(Wg + (size_t)row * 512 + (it + 1) * 64 + ((ch ^ (row & 7)) << 3),
               Bnxt + cid * 8);
      }
    }
#pragma unroll
    for (int fi = 0; fi < 2; ++fi) {
      bf16x8 af[4], bfr[2];
#pragma unroll
      for (int mi = 0; mi < 4; ++mi) {
        int arow = wr * 64 + mi * 16 + c;
        af[mi] = *reinterpret_cast<const bf16x8*>(
            &plds[arow * 64 + (((fi * 4 + g) ^ (arow & 7)) << 3)]);
      }
#pragma unroll
      for (int ni = 0; ni < 2; ++ni) {
        int brow = wc * 32 + ni * 16 + c;
        bfr[ni] = *reinterpret_cast<const bf16x8*>(
            &Bcur[brow * 64 + (((fi * 4 + g) ^ (brow & 7)) << 3)]);
      }
      __builtin_amdgcn_s_setprio(1);
#pragma unroll
      for (int mi = 0; mi < 4; ++mi)
#pragma unroll
        for (int ni = 0; ni < 2; ++ni)
          acc[mi][ni] = __builtin_amdgcn_mfma_f32_16x16x32_bf16(af[mi], bfr[ni], acc[mi][ni], 0, 0, 0);
      __builtin_amdgcn_s_setprio(0);
    }
  }

  // ---- coalesced epilogue via LDS (plds[0..16383] = 32KB tile) ----
  const float* bias_arr[5] = {b0, b1, b2, b3, b4};
  const float* bias = bias_arr[proj];
  float scale = (proj < 2) ? QSCALE : 1.0f;
  int bglob = rb >> 4;
  int lbase = (rb & 15) * 128;
  __syncthreads();
  if (proj < 4) {
    unsigned short* qkdst = (proj < 2) ? qws : kws;
    int half = (proj & 1) ? 64 : 0;
#pragma unroll
    for (int ni = 0; ni < 2; ++ni) {
      int col = wc * 32 + ni * 16 + c;
      int colch = col >> 3, cw = col & 7;
      float bv = bias[cb * 128 + col];
#pragma unroll
      for (int mi = 0; mi < 4; ++mi)
#pragma unroll
        for (int rr = 0; rr < 4; ++rr) {
          int l_loc = wr * 64 + mi * 16 + g * 4 + rr;
          float v = (acc[mi][ni][rr] + bv) * scale;
          plds[l_loc * 128 + ((colch ^ (l_loc & 15)) << 3) + cw] = f2bfu(v);
        }
    }
    __syncthreads();
#pragma unroll
    for (int j = 0; j < 4; ++j) {
      int q = t + j * 512;
      int l_loc = q >> 4, ch = q & 15;
      uint4 d = *reinterpret_cast<const uint4*>(
          &plds[l_loc * 128 + ((ch ^ (l_loc & 15)) << 3)]);
      int n0 = cb * 128 + ch * 8;
      int h = n0 >> 6, a0 = n0 & 63;
      *reinterpret_cast<uint4*>(
          &qkdst[((size_t)(bglob * 8 + h) * 2048 + lbase + l_loc) * 128 + half + a0]) = d;
    }
  } else {
#pragma unroll
    for (int ni = 0; ni < 2; ++ni) {
      int n_loc = wc * 32 + ni * 16 + c;
      float bv = bias[cb * 128 + n_loc];
#pragma unroll
      for (int mi = 0; mi < 4; ++mi) {
        int P = ((mi & 2) << 4) | (g << 3) | ((mi & 1) << 2);
        int lp = wr * 64 + P;
        int c16 = lp >> 3, h8 = (lp >> 2) & 1;
        uint2 pk;
        pk.x = (uint32_t)f2bfu(acc[mi][ni][0] + bv) |
               ((uint32_t)f2bfu(acc[mi][ni][1] + bv) << 16);
        pk.y = (uint32_t)f2bfu(acc[mi][ni][2] + bv) |
               ((uint32_t)f2bfu(acc[mi][ni][3] + bv) << 16);
        *reinterpret_cast<uint2*>(
            &plds[(n_loc * 16 + (c16 ^ (n_loc & 15))) * 8 + h8 * 4]) = pk;
      }
    }
    __syncthreads();
#pragma unroll
    for (int j = 0; j < 4; ++j) {
      int q = t + j * 512;
      int n_loc = q & 127, c16 = q >> 7;
      uint4 d = *reinterpret_cast<const uint4*>(
          &plds[(n_loc * 16 + (c16 ^ (n_loc & 15))) * 8]);
      int n0 = cb * 128 + n_loc;
      int h = n0 >> 6, a = n0 & 63;
      *reinterpret_cast<uint4*>(
          &vws[((size_t)(bglob * 8 + h) * 64 + a) * 2048 + lbase + c16 * 8]) = d;
    }
  }
}

// ---- K2: flash attention (R18 verbatim) ----
__global__ __launch_bounds__(256) void k_attn(
    const unsigned short* __restrict__ qws, const unsigned short* __restrict__ kws,
    const unsigned short* __restrict__ vws, unsigned short* __restrict__ ctxb) {
  __shared__ __align__(16) unsigned short alds[24576];  // Kb0[8192]|Kb1[8192]|Vb0[4096]|Vb1[4096]
  int orig = blockIdx.x;
  int xcd = orig & 7, j = orig >> 3;
  int bh = xcd * 4 + (j >> 4), qb = j & 15;
  int t = threadIdx.x;
  int w = t >> 6, lane = t & 63, g = lane >> 4, c = lane & 15;

  const unsigned short* Kg = kws + (size_t)bh * 2048 * 128;
  const unsigned short* Vg = vws + (size_t)bh * 64 * 2048;

  bf16x8 qf[2][4];
#pragma unroll
  for (int qt = 0; qt < 2; ++qt) {
    const unsigned short* Qg =
        qws + ((size_t)bh * 2048 + qb * 128 + w * 32 + qt * 16 + c) * 128;
#pragma unroll
    for (int fi = 0; fi < 4; ++fi)
      qf[qt][fi] = *reinterpret_cast<const bf16x8*>(Qg + fi * 32 + g * 8);
  }

  f32x4 o[2][4];
#pragma unroll
  for (int qt = 0; qt < 2; ++qt)
#pragma unroll
    for (int at = 0; at < 4; ++at) o[qt][at] = f32x4{0.f, 0.f, 0.f, 0.f};
  float lsum[2] = {0.f, 0.f};

#pragma unroll
  for (int jj = 0; jj < 4; ++jj) {
    int cid = t + jj * 256;
    int row = cid >> 4, ch = cid & 15;
    glds16(Kg + (size_t)row * 128 + ((ch ^ (row & 15)) << 3), alds + cid * 8);
  }
#pragma unroll
  for (int jj = 0; jj < 2; ++jj) {
    int cid = t + jj * 256;
    int a = cid >> 3, ch = cid & 7;
    glds16(Vg + (size_t)a * 2048 + ((ch ^ (a & 7)) << 3), alds + 16384 + cid * 8);
  }
  __syncthreads();

#pragma unroll 1
  for (int it = 0; it < 32; ++it) {
    int cur = it & 1;
    unsigned short* Kcur = alds + cur * 8192;
    unsigned short* Vcur = alds + 16384 + cur * 4096;
    if (it < 31) {
      unsigned short* Knxt = alds + (cur ^ 1) * 8192;
      unsigned short* Vnxt = alds + 16384 + (cur ^ 1) * 4096;
#pragma unroll
      for (int jj = 0; jj < 4; ++jj) {
        int cid = t + jj * 256;
        int row = cid >> 4, ch = cid & 15;
        glds16(Kg + ((size_t)(it + 1) * 64 + row) * 128 + ((ch ^ (row & 15)) << 3),
               Knxt + cid * 8);
      }
#pragma unroll
      for (int jj = 0; jj < 2; ++jj) {
        int cid = t + jj * 256;
        int a = cid >> 3, ch = cid & 7;
        glds16(Vg + (size_t)a * 2048 + (it + 1) * 64 + ((ch ^ (a & 7)) << 3),
               Vnxt + cid * 8);
      }
    }

    f32x4 s[2][4];
#pragma unroll
    for (int qt = 0; qt < 2; ++qt)
#pragma unroll
      for (int mt = 0; mt < 4; ++mt) s[qt][mt] = f32x4{0.f, 0.f, 0.f, 0.f};
#pragma unroll
    for (int fi = 0; fi < 4; ++fi) {
      bf16x8 kf[4];
#pragma unroll
      for (int mt = 0; mt < 4; ++mt)
        kf[mt] = *reinterpret_cast<const bf16x8*>(
            &Kcur[(mt * 16 + c) * 128 + (((fi * 4 + g) ^ c) << 3)]);
      __builtin_amdgcn_s_setprio(1);
#pragma unroll
      for (int mt = 0; mt < 4; ++mt) {
        s[0][mt] = __builtin_amdgcn_mfma_f32_16x16x32_bf16(kf[mt], qf[0][fi], s[0][mt], 0, 0, 0);
        s[1][mt] = __builtin_amdgcn_mfma_f32_16x16x32_bf16(kf[mt], qf[1][fi], s[1][mt], 0, 0, 0);
      }
      __builtin_amdgcn_s_setprio(0);
    }

    uint32_t pku[2][4][2];
#pragma unroll
    for (int qt = 0; qt < 2; ++qt) {
      float ls = 0.f;
#pragma unroll
      for (int mt = 0; mt < 4; ++mt) {
        float p0 = EXP2F(s[qt][mt][0]);
        float p1 = EXP2F(s[qt][mt][1]);
        float p2 = EXP2F(s[qt][mt][2]);
        float p3 = EXP2F(s[qt][mt][3]);
        ls += (p0 + p1) + (p2 + p3);
        pku[qt][mt][0] = pack_trunc(p0, p1);
        pku[qt][mt][1] = pack_trunc(p2, p3);
      }
      lsum[qt] += ls;
    }

    union u32x4_bf { uint32_t u[4]; bf16x8 v; };
    u32x4_bf pf[2][2];
#pragma unroll
    for (int qt = 0; qt < 2; ++qt) {
      pf[qt][0].u[0] = pku[qt][0][0]; pf[qt][0].u[1] = pku[qt][0][1];
      pf[qt][0].u[2] = pku[qt][1][0]; pf[qt][0].u[3] = pku[qt][1][1];
      pf[qt][1].u[0] = pku[qt][2][0]; pf[qt][1].u[1] = pku[qt][2][1];
      pf[qt][1].u[2] = pku[qt][3][0]; pf[qt][1].u[3] = pku[qt][3][1];
    }
#pragma unroll
    for (int at = 0; at < 4; ++at) {
      int arow = at * 16 + c;
      bf16x8 vf0 = *reinterpret_cast<const bf16x8*>(
          &Vcur[arow * 64 + ((g ^ (arow & 7)) << 3)]);
      bf16x8 vf1 = *reinterpret_cast<const bf16x8*>(
          &Vcur[arow * 64 + (((4 + g) ^ (arow & 7)) << 3)]);
      __builtin_amdgcn_s_setprio(1);
#pragma unroll
      for (int qt = 0; qt < 2; ++qt) {
        o[qt][at] = __builtin_amdgcn_mfma_f32_16x16x32_bf16(pf[qt][0].v, vf0, o[qt][at], 0, 0, 0);
        o[qt][at] = __builtin_amdgcn_mfma_f32_16x16x32_bf16(pf[qt][1].v, vf1, o[qt][at], 0, 0, 0);
      }
      __builtin_amdgcn_s_setprio(0);
    }
    __syncthreads();
  }

  int b = bh >> 3, h = bh & 7;
#pragma unroll
  for (int qt = 0; qt < 2; ++qt) {
    lsum[qt] += __shfl_xor(lsum[qt], 16);
    lsum[qt] += __shfl_xor(lsum[qt], 32);
    float rinv[4];
#pragma unroll
    for (int r = 0; r < 4; ++r) rinv[r] = 1.0f / __shfl(lsum[qt], g * 4 + r);
#pragma unroll
    for (int at = 0; at < 4; ++at) {
      int col = at * 16 + c;
      int colch = col >> 3, cw = col & 7;
#pragma unroll
      for (int r = 0; r < 4; ++r) {
        int l_loc = w * 32 + qt * 16 + g * 4 + r;
        alds[l_loc * 64 + ((colch ^ (l_loc & 7)) << 3) + cw] = f2bfu(o[qt][at][r] * rinv[r]);
      }
    }
  }
  __syncthreads();
#pragma unroll
  for (int jj = 0; jj < 4; ++jj) {
    int q = t + jj * 256;
    int l_loc = q >> 3, ch = q & 7;
    uint4 d = *reinterpret_cast<const uint4*>(
        &alds[l_loc * 64 + ((ch ^ (l_loc & 7)) << 3)]);
    *reinterpret_cast<uint4*>(
        &ctxb[(size_t)(b * 2048 + qb * 128 + l_loc) * 512 + h * 64 + ch * 8]) = d;
  }
}

// ---- K3: out-proj + bias + residual + LAYERNORM fused -> d_out f32 ----
// Block = 64 rows x full 512 cols (full row => LN in-block). 8 waves, wave w owns
// cols w*64..w*64+64. Epilogue: per 32-row half, f32 LDS tile -> coalesced read with
// resid, per-row shfl stats (16 lanes/row), normalize, coalesced store.
__global__ __launch_bounds__(512) void k_oproj_ln(
    const unsigned short* __restrict__ ctxb, const unsigned short* __restrict__ wt,
    const float* __restrict__ bo, const float* __restrict__ resid,
    const float* __restrict__ gam, const float* __restrict__ bet,
    float* __restrict__ out) {
  __shared__ __align__(16) unsigned short olds[36864];  // Bl[32768] | Al[4096]
  int rb = blockIdx.x;  // 128 blocks, rows rb*64
  const unsigned short* Ag = ctxb + (size_t)rb * 64 * 512;
  const unsigned short* Wg = wt + (size_t)5 * 262144;  // all 512 out-rows
  int t = threadIdx.x;
  int lane = t & 63, w = t >> 6, g = lane >> 4, c = lane & 15;
  unsigned short* Bl = olds;
  unsigned short* Al = olds + 32768;
  f32x4 acc[4][4];  // [mi rows][ni cols]
#pragma unroll
  for (int i = 0; i < 4; ++i)
#pragma unroll
    for (int j = 0; j < 4; ++j) acc[i][j] = f32x4{0.f, 0.f, 0.f, 0.f};

#pragma unroll 1
  for (int it = 0; it < 8; ++it) {
    __syncthreads();
    {  // A: 64 rows x 8 chunks = 512 cells, 1/thread
      int row = t >> 3, ch = t & 7;
      glds16(Ag + (size_t)row * 512 + it * 64 + ((ch ^ (row & 7)) << 3), Al + t * 8);
    }
#pragma unroll
    for (int j = 0; j < 8; ++j) {  // B: 512 rows x 8 chunks = 4096 cells, 8/thread
      int cid = t + j * 512;
      int row = cid >> 3, ch = cid & 7;
      glds16(Wg + (size_t)row * 512 + it * 64 + ((ch ^ (row & 7)) << 3), Bl + cid * 8);
    }
    __syncthreads();
#pragma unroll
    for (int fi = 0; fi < 2; ++fi) {
      bf16x8 af[4], bfr[4];
#pragma unroll
      for (int mi = 0; mi < 4; ++mi) {
        int arow = mi * 16 + c;
        af[mi] = *reinterpret_cast<const bf16x8*>(
            &Al[arow * 64 + (((fi * 4 + g) ^ (arow & 7)) << 3)]);
      }
#pragma unroll
      for (int ni = 0; ni < 4; ++ni) {
        int brow = w * 64 + ni * 16 + c;
        bfr[ni] = *reinterpret_cast<const bf16x8*>(
            &Bl[brow * 64 + (((fi * 4 + g) ^ (brow & 7)) << 3)]);
      }
      __builtin_amdgcn_s_setprio(1);
#pragma unroll
      for (int mi = 0; mi < 4; ++mi)
#pragma unroll
        for (int ni = 0; ni < 4; ++ni)
          acc[mi][ni] = __builtin_amdgcn_mfma_f32_16x16x32_bf16(af[mi], bfr[ni], acc[mi][ni], 0, 0, 0);
      __builtin_amdgcn_s_setprio(0);
    }
  }

  // ---- fused epilogue: two 32-row halves through f32 tile (Bl region, 64KB) ----
  float* fl = reinterpret_cast<float*>(olds);  // [32 rows][512 cols] f32, chunk-swizzled
  int erow = t >> 4;        // 0..31 (row within half)
  int ei = t & 15;          // 16 threads per row, 32 cols each
#pragma unroll 1
  for (int h = 0; h < 2; ++h) {
    __syncthreads();  // tile region free (prev half / staging done)
#pragma unroll
    for (int mi2 = 0; mi2 < 2; ++mi2) {
      int mi = h * 2 + mi2;
#pragma unroll
      for (int ni = 0; ni < 4; ++ni) {
        int col = w * 64 + ni * 16 + c;
        int colch = col >> 2, cw = col & 3;
        float bv = bo[col];
#pragma unroll
        for (int r = 0; r < 4; ++r) {
          int l_loc = mi2 * 16 + g * 4 + r;
          fl[l_loc * 512 + ((colch ^ (l_loc & 7)) << 2) + cw] = acc[mi][ni][r] + bv;
        }
      }
    }
    __syncthreads();
    // coalesced read + resid; stats over full row (16 lanes x 32 cols)
    int rowg = rb * 64 + h * 32 + erow;
    f32x4 xv[8];
    float sum = 0.f, ssq = 0.f;
#pragma unroll
    for (int k = 0; k < 8; ++k) {
      int ci = ei * 8 + ((k + ei) & 7);  // rotated chunk order (bank spread)
      f32x4 v = *reinterpret_cast<const f32x4*>(
          &fl[erow * 512 + (((ci) ^ (erow & 7)) << 2)]);
      f32x4 rs = *reinterpret_cast<const f32x4*>(&resid[(size_t)rowg * 512 + ci * 4]);
      v = v + rs;
      xv[k] = v;
      sum += v[0] + v[1] + v[2] + v[3];
      ssq += v[0] * v[0] + v[1] * v[1] + v[2] * v[2] + v[3] * v[3];
    }
#pragma unroll
    for (int d = 1; d < 16; d <<= 1) {
      sum += __shfl_xor(sum, d);
      ssq += __shfl_xor(ssq, d);
    }
    float mu = sum * (1.0f / 512.0f);
    float var = ssq * (1.0f / 512.0f) - mu * mu;
    float rstd = rsqrtf(var + 1e-5f);
#pragma unroll
    for (int k = 0; k < 8; ++k) {
      int ci = ei * 8 + ((k + ei) & 7);
      f32x4 gm = *reinterpret_cast<const f32x4*>(&gam[ci * 4]);
      f32x4 bt = *reinterpret_cast<const f32x4*>(&bet[ci * 4]);
      f32x4 v = xv[k];
#pragma unroll
      for (int e = 0; e < 4; ++e) v[e] = (v[e] - mu) * rstd * gm[e] + bt[e];
      *reinterpret_cast<f32x4*>(&out[(size_t)rowg * 512 + ci * 4]) = v;
    }
  }
}

extern "C" void kernel_launch(void* const* d_in, const int* in_sizes, int n_in,
                              void* d_out, int out_size, void* d_ws, size_t ws_size,
                              hipStream_t stream) {
  const float* Qd  = (const float*)d_in[0];
  const float* Qt  = (const float*)d_in[1];
  const float* Kd  = (const float*)d_in[2];
  const float* Kt  = (const float*)d_in[3];
  const float* Vt  = (const float*)d_in[4];
  const float* Wqd = (const float*)d_in[5];
  const float* bqd = (const float*)d_in[6];
  const float* Wqt = (const float*)d_in[7];
  const float* bqt = (const float*)d_in[8];
  const float* Wkd = (const float*)d_in[9];
  const float* bkd = (const float*)d_in[10];
  const float* Wkt = (const float*)d_in[11];
  const float* bkt = (const float*)d_in[12];
  const float* Wvt = (const float*)d_in[13];
  const float* bvt = (const float*)d_in[14];
  const float* Wo  = (const float*)d_in[15];
  const float* bo  = (const float*)d_in[16];
  const float* lng = (const float*)d_in[17];
  const float* lnb = (const float*)d_in[18];

  char* ws = (char*)d_ws;
  unsigned short* wt   = (unsigned short*)(ws);
  unsigned short* qws  = (unsigned short*)(ws + 3145728);
  unsigned short* kws  = (unsigned short*)(ws + 19922944);
  unsigned short* vws  = (unsigned short*)(ws + 36700160);
  unsigned short* ctxb = (unsigned short*)(ws + 45088768);
  float* out = (float*)d_out;

  k_prep_w<<<384, 256, 0, stream>>>(Wqd, Wqt, Wkd, Wkt, Wvt, Wo, wt);
  k_proj2<<<1280, 512, 0, stream>>>(Qd, Qt, Kd, Kt, Vt, wt,
                                    bqd, bqt, bkd, bkt, bvt, qws, kws, vws);
  k_attn<<<512, 256, 0, stream>>>(qws, kws, vws, ctxb);
  k_oproj_ln<<<128, 512, 0, stream>>>(ctxb, wt, bo, Qd, lng, lnb, out);
}

// Round 20
// 127.457 us; speedup vs baseline: 1.2672x; 1.2672x over previous
//
#include <hip/hip_runtime.h>
#include <hip/hip_bf16.h>
#include <stdint.h>

// MixAttention: B=4, L=2048, D=512, H=8, A=64
// ws layout (bytes):
//  wt   @ 0        : 6*512*512*2   = 3145728   (W^T bf16, [mat][out][in])
//  qws  @ 3145728  : 32*2048*128*2 = 16777216  (Q' = [qd|qt]*0.125*log2e, [bh][l][128])
//  kws  @ 19922944 : 16777216                  (K' = [kd|kt], [bh][l][128])
//  vws  @ 36700160 : 32*64*2048*2  = 8388608   (V^T, [bh][a][l'], l' pi-permuted in 64-blocks)
//  ctxb @ 45088768 : 8192*512*2    = 8388608   (attn out, [row][512])

using f32x4  = __attribute__((ext_vector_type(4))) float;
using bf16x8 = __attribute__((ext_vector_type(8))) short;

typedef __attribute__((address_space(1))) const uint32_t g_u32;
typedef __attribute__((address_space(3))) uint32_t l_u32;

#if __has_builtin(__builtin_amdgcn_exp2f)
#define EXP2F __builtin_amdgcn_exp2f
#else
#define EXP2F exp2f
#endif
#define QSCALE 0.1803368801111204f  /* 0.125 * log2(e): scores in log2 units */

__device__ __forceinline__ void glds16(const void* g, void* l) {
  __builtin_amdgcn_global_load_lds((g_u32*)g, (l_u32*)l, 16, 0, 0);
}

__device__ __forceinline__ unsigned short f2bfu(float f) {
  __hip_bfloat16 h = __float2bfloat16(f);
  union { __hip_bfloat16 h; unsigned short u; } v;
  v.h = h;
  return v.u;
}

// pack two non-negative finite floats to 2xbf16 by truncation (1 v_perm_b32)
__device__ __forceinline__ uint32_t pack_trunc(float lo, float hi) {
  union { float f; uint32_t u; } a, b;
  a.f = lo; b.f = hi;
  return __builtin_amdgcn_perm(b.u, a.u, 0x07060302u);
}

// ---------------- K0a: W [512 in][512 out] f32 -> W^T [out][in] bf16 ----------------
__global__ __launch_bounds__(256) void k_prep_w(
    const float* __restrict__ w0, const float* __restrict__ w1,
    const float* __restrict__ w2, const float* __restrict__ w3,
    const float* __restrict__ w4, const float* __restrict__ w5,
    unsigned short* __restrict__ wt) {
  __shared__ float tile[64][68];
  const float* wsrc[6] = {w0, w1, w2, w3, w4, w5};
  int bid = blockIdx.x;
  int mat = bid >> 6, tid = bid & 63;
  int k0 = (tid >> 3) << 6, c0 = (tid & 7) << 6;
  const float* w = wsrc[mat];
  int t = threadIdx.x;
  {
    int r = t >> 2, cq = (t & 3) << 4;
    const float4* src = reinterpret_cast<const float4*>(w + (size_t)(k0 + r) * 512 + c0 + cq);
#pragma unroll
    for (int j = 0; j < 4; ++j) {
      float4 v = src[j];
      tile[r][cq + j * 4 + 0] = v.x;
      tile[r][cq + j * 4 + 1] = v.y;
      tile[r][cq + j * 4 + 2] = v.z;
      tile[r][cq + j * 4 + 3] = v.w;
    }
  }
  __syncthreads();
  {
    int cc = t >> 2, kq = (t & 3) << 4;
    union { unsigned short u[16]; uint4 v[2]; } p;
#pragma unroll
    for (int j = 0; j < 16; ++j) p.u[j] = f2bfu(tile[kq + j][cc]);
    unsigned short* dst = wt + (size_t)mat * 262144 + (size_t)(c0 + cc) * 512 + k0 + kq;
    *reinterpret_cast<uint4*>(dst)     = p.v[0];
    *reinterpret_cast<uint4*>(dst + 8) = p.v[1];
  }
}

// ---- K1: 5 projections, 128x128 tile, 8 waves; A reg-prefetch + B glds16 dbuf.
//      Coalesced epilogue via LDS round-trip (scattered 2B stores -> 16B coalesced).
__global__ __launch_bounds__(512) void k_proj2(
    const float* __restrict__ x0, const float* __restrict__ x1,
    const float* __restrict__ x2, const float* __restrict__ x3,
    const float* __restrict__ x4,
    const unsigned short* __restrict__ wt,
    const float* __restrict__ b0, const float* __restrict__ b1,
    const float* __restrict__ b2, const float* __restrict__ b3,
    const float* __restrict__ b4,
    unsigned short* __restrict__ qws, unsigned short* __restrict__ kws,
    unsigned short* __restrict__ vws) {
  __shared__ __align__(16) unsigned short plds[24576];  // Abuf[8192] | Bbuf0[8192] | Bbuf1[8192]
  int bid = blockIdx.x;
  int proj = bid >> 8, rem = bid & 255;
  int cb = rem >> 6, rb = rem & 63;
  const float* xs[5] = {x0, x1, x2, x3, x4};
  const float* Ag = xs[proj] + (size_t)rb * 128 * 512;
  const unsigned short* Wg = wt + (size_t)proj * 262144 + (size_t)cb * 128 * 512;
  int t = threadIdx.x;
  int lane = t & 63, w = t >> 6, wr = w >> 2, wc = w & 3, g = lane >> 4, c = lane & 15;
  f32x4 acc[4][2];
#pragma unroll
  for (int i = 0; i < 4; ++i)
#pragma unroll
    for (int j = 0; j < 2; ++j) acc[i][j] = f32x4{0.f, 0.f, 0.f, 0.f};

  int srow[2], sch[2];
#pragma unroll
  for (int j = 0; j < 2; ++j) {
    int q = t + j * 512;
    srow[j] = q >> 3;
    sch[j] = q & 7;
  }
  float4 pa[2], pb[2];
#pragma unroll
  for (int j = 0; j < 2; ++j) {
    const float* src = Ag + (size_t)srow[j] * 512 + sch[j] * 8;
    pa[j] = *reinterpret_cast<const float4*>(src);
    pb[j] = *reinterpret_cast<const float4*>(src + 4);
  }
#pragma unroll
  for (int j = 0; j < 2; ++j) {
    int cid = t + j * 512;
    int row = cid >> 3, ch = cid & 7;
    glds16(Wg + (size_t)row * 512 + ((ch ^ (row & 7)) << 3),
           plds + 8192 + cid * 8);
  }

#pragma unroll 1
  for (int it = 0; it < 8; ++it) {
    int cur = it & 1;
    unsigned short* Bcur = plds + 8192 + cur * 8192;
    unsigned short* Bnxt = plds + 8192 + (cur ^ 1) * 8192;
    __syncthreads();  // drains A-regs + B(it) glds16 (issued a full compute-phase ago)
#pragma unroll
    for (int j = 0; j < 2; ++j) {
      union { unsigned short u[8]; uint4 v; } p;
      p.u[0] = f2bfu(pa[j].x); p.u[1] = f2bfu(pa[j].y);
      p.u[2] = f2bfu(pa[j].z); p.u[3] = f2bfu(pa[j].w);
      p.u[4] = f2bfu(pb[j].x); p.u[5] = f2bfu(pb[j].y);
      p.u[6] = f2bfu(pb[j].z); p.u[7] = f2bfu(pb[j].w);
      *reinterpret_cast<uint4*>(&plds[srow[j] * 64 + ((sch[j] ^ (srow[j] & 7)) << 3)]) = p.v;
    }
    __syncthreads();  // drains only lgkm (A ds_write) -- cheap
    if (it < 7) {
#pragma unroll
      for (int j = 0; j < 2; ++j) {
        const float* src = Ag + (size_t)srow[j] * 512 + (it + 1) * 64 + sch[j] * 8;
        pa[j] = *reinterpret_cast<const float4*>(src);
        pb[j] = *reinterpret_cast<const float4*>(src + 4);
      }
#pragma unroll
      for (int j = 0; j < 2; ++j) {
        int cid = t + j * 512;
        int row = cid >> 3, ch = cid & 7;
        glds16(Wg + (size_t)row * 512 + (it + 1) * 64 + ((ch ^ (row & 7)) << 3),
               Bnxt + cid * 8);
      }
    }
#pragma unroll
    for (int fi = 0; fi < 2; ++fi) {
      bf16x8 af[4], bfr[2];
#pragma unroll
      for (int mi = 0; mi < 4; ++mi) {
        int arow = wr * 64 + mi * 16 + c;
        af[mi] = *reinterpret_cast<const bf16x8*>(
            &plds[arow * 64 + (((fi * 4 + g) ^ (arow & 7)) << 3)]);
      }
#pragma unroll
      for (int ni = 0; ni < 2; ++ni) {
        int brow = wc * 32 + ni * 16 + c;
        bfr[ni] = *reinterpret_cast<const bf16x8*>(
            &Bcur[brow * 64 + (((fi * 4 + g) ^ (brow & 7)) << 3)]);
      }
      __builtin_amdgcn_s_setprio(1);
#pragma unroll
      for (int mi = 0; mi < 4; ++mi)
#pragma unroll
        for (int ni = 0; ni < 2; ++ni)
          acc[mi][ni] = __builtin_amdgcn_mfma_f32_16x16x32_bf16(af[mi], bfr[ni], acc[mi][ni], 0, 0, 0);
      __builtin_amdgcn_s_setprio(0);
    }
  }

  // ---- coalesced epilogue via LDS (plds[0..16383] = 32KB tile) ----
  const float* bias_arr[5] = {b0, b1, b2, b3, b4};
  const float* bias = bias_arr[proj];
  float scale = (proj < 2) ? QSCALE : 1.0f;
  int bglob = rb >> 4;            // batch index (rows rb*128 span one batch)
  int lbase = (rb & 15) * 128;    // l offset within [0,2048)
  __syncthreads();                // compute done; safe to reuse staging LDS
  if (proj < 4) {
    unsigned short* qkdst = (proj < 2) ? qws : kws;
    int half = (proj & 1) ? 64 : 0;
    // write [128 l][128 n] bf16, n in 8-col chunks XOR-swizzled by l&15
#pragma unroll
    for (int ni = 0; ni < 2; ++ni) {
      int col = wc * 32 + ni * 16 + c;
      int colch = col >> 3, cw = col & 7;
      float bv = bias[cb * 128 + col];
#pragma unroll
      for (int mi = 0; mi < 4; ++mi)
#pragma unroll
        for (int rr = 0; rr < 4; ++rr) {
          int l_loc = wr * 64 + mi * 16 + g * 4 + rr;
          float v = (acc[mi][ni][rr] + bv) * scale;
          plds[l_loc * 128 + ((colch ^ (l_loc & 15)) << 3) + cw] = f2bfu(v);
        }
    }
    __syncthreads();
#pragma unroll
    for (int j = 0; j < 4; ++j) {
      int q = t + j * 512;
      int l_loc = q >> 4, ch = q & 15;
      uint4 d = *reinterpret_cast<const uint4*>(
          &plds[l_loc * 128 + ((ch ^ (l_loc & 15)) << 3)]);
      int n0 = cb * 128 + ch * 8;
      int h = n0 >> 6, a0 = n0 & 63;
      *reinterpret_cast<uint4*>(
          &qkdst[((size_t)(bglob * 8 + h) * 2048 + lbase + l_loc) * 128 + half + a0]) = d;
    }
  } else {
    // V: write [128 n][128 lperm] bf16 (b64 per (mi,ni)), 16B chunks XOR-swizzled by n&15
#pragma unroll
    for (int ni = 0; ni < 2; ++ni) {
      int n_loc = wc * 32 + ni * 16 + c;
      float bv = bias[cb * 128 + n_loc];
#pragma unroll
      for (int mi = 0; mi < 4; ++mi) {
        int P = ((mi & 2) << 4) | (g << 3) | ((mi & 1) << 2);  // perm base; rr = low 2 bits
        int lp = wr * 64 + P;
        int c16 = lp >> 3, h8 = (lp >> 2) & 1;
        uint2 pk;
        pk.x = (uint32_t)f2bfu(acc[mi][ni][0] + bv) |
               ((uint32_t)f2bfu(acc[mi][ni][1] + bv) << 16);
        pk.y = (uint32_t)f2bfu(acc[mi][ni][2] + bv) |
               ((uint32_t)f2bfu(acc[mi][ni][3] + bv) << 16);
        *reinterpret_cast<uint2*>(
            &plds[(n_loc * 16 + (c16 ^ (n_loc & 15))) * 8 + h8 * 4]) = pk;
      }
    }
    __syncthreads();
#pragma unroll
    for (int j = 0; j < 4; ++j) {
      int q = t + j * 512;
      int n_loc = q & 127, c16 = q >> 7;
      uint4 d = *reinterpret_cast<const uint4*>(
          &plds[(n_loc * 16 + (c16 ^ (n_loc & 15))) * 8]);
      int n0 = cb * 128 + n_loc;
      int h = n0 >> 6, a = n0 & 63;
      *reinterpret_cast<uint4*>(
          &vws[((size_t)(bglob * 8 + h) * 64 + a) * 2048 + lbase + c16 * 8]) = d;
    }
  }
}

// ---------------- shared GEMM core: 64x64 tile (k_oproj) ----------------
__device__ __forceinline__ void gemm_core(
    const unsigned short* Ag, const unsigned short* Wg,
    unsigned short* Al, unsigned short* Bl, f32x4 acc[4]) {
  int t = threadIdx.x;
  int lane = t & 63, w = t >> 6, g = lane >> 4, c = lane & 15;
#pragma unroll 1
  for (int it = 0; it < 8; ++it) {
    __syncthreads();
#pragma unroll
    for (int j = 0; j < 2; ++j) {
      int cid = t + j * 256;
      int row = cid >> 3, ch = cid & 7;
      glds16(Ag + (size_t)row * 512 + it * 64 + ((ch ^ (row & 7)) << 3), Al + cid * 8);
      glds16(Wg + (size_t)row * 512 + it * 64 + ((ch ^ (row & 7)) << 3), Bl + cid * 8);
    }
    __syncthreads();
#pragma unroll
    for (int fi = 0; fi < 2; ++fi) {
      int arow = w * 16 + c;
      bf16x8 af = *reinterpret_cast<const bf16x8*>(
          Al + arow * 64 + (((fi * 4 + g) ^ (arow & 7)) << 3));
#pragma unroll
      for (int ct = 0; ct < 4; ++ct) {
        int brow = ct * 16 + c;
        bf16x8 bf = *reinterpret_cast<const bf16x8*>(
            Bl + brow * 64 + (((fi * 4 + g) ^ (brow & 7)) << 3));
        acc[ct] = __builtin_amdgcn_mfma_f32_16x16x32_bf16(af, bf, acc[ct], 0, 0, 0);
      }
    }
  }
}

// ---- K2: flash attention, static-max softmax, P in regs, b128 V reads (pi-permuted),
//      coalesced ctxb epilogue via LDS ----
__global__ __launch_bounds__(256) void k_attn(
    const unsigned short* __restrict__ qws, const unsigned short* __restrict__ kws,
    const unsigned short* __restrict__ vws, unsigned short* __restrict__ ctxb) {
  __shared__ __align__(16) unsigned short alds[24576];  // Kb0[8192]|Kb1[8192]|Vb0[4096]|Vb1[4096]
  int orig = blockIdx.x;
  int xcd = orig & 7, j = orig >> 3;
  int bh = xcd * 4 + (j >> 4), qb = j & 15;  // 16 q-blocks of 128 rows
  int t = threadIdx.x;
  int w = t >> 6, lane = t & 63, g = lane >> 4, c = lane & 15;

  const unsigned short* Kg = kws + (size_t)bh * 2048 * 128;
  const unsigned short* Vg = vws + (size_t)bh * 64 * 2048;

  bf16x8 qf[2][4];
#pragma unroll
  for (int qt = 0; qt < 2; ++qt) {
    const unsigned short* Qg =
        qws + ((size_t)bh * 2048 + qb * 128 + w * 32 + qt * 16 + c) * 128;
#pragma unroll
    for (int fi = 0; fi < 4; ++fi)
      qf[qt][fi] = *reinterpret_cast<const bf16x8*>(Qg + fi * 32 + g * 8);
  }

  f32x4 o[2][4];
#pragma unroll
  for (int qt = 0; qt < 2; ++qt)
#pragma unroll
    for (int at = 0; at < 4; ++at) o[qt][at] = f32x4{0.f, 0.f, 0.f, 0.f};
  float lsum[2] = {0.f, 0.f};

#pragma unroll
  for (int jj = 0; jj < 4; ++jj) {
    int cid = t + jj * 256;
    int row = cid >> 4, ch = cid & 15;
    glds16(Kg + (size_t)row * 128 + ((ch ^ (row & 15)) << 3), alds + cid * 8);
  }
#pragma unroll
  for (int jj = 0; jj < 2; ++jj) {
    int cid = t + jj * 256;
    int a = cid >> 3, ch = cid & 7;
    glds16(Vg + (size_t)a * 2048 + ((ch ^ (a & 7)) << 3), alds + 16384 + cid * 8);
  }
  __syncthreads();

#pragma unroll 1
  for (int it = 0; it < 32; ++it) {
    int cur = it & 1;
    unsigned short* Kcur = alds + cur * 8192;
    unsigned short* Vcur = alds + 16384 + cur * 4096;
    if (it < 31) {
      unsigned short* Knxt = alds + (cur ^ 1) * 8192;
      unsigned short* Vnxt = alds + 16384 + (cur ^ 1) * 4096;
#pragma unroll
      for (int jj = 0; jj < 4; ++jj) {
        int cid = t + jj * 256;
        int row = cid >> 4, ch = cid & 15;
        glds16(Kg + ((size_t)(it + 1) * 64 + row) * 128 + ((ch ^ (row & 15)) << 3),
               Knxt + cid * 8);
      }
#pragma unroll
      for (int jj = 0; jj < 2; ++jj) {
        int cid = t + jj * 256;
        int a = cid >> 3, ch = cid & 7;
        glds16(Vg + (size_t)a * 2048 + (it + 1) * 64 + ((ch ^ (a & 7)) << 3),
               Vnxt + cid * 8);
      }
    }

    f32x4 s[2][4];
#pragma unroll
    for (int qt = 0; qt < 2; ++qt)
#pragma unroll
      for (int mt = 0; mt < 4; ++mt) s[qt][mt] = f32x4{0.f, 0.f, 0.f, 0.f};
#pragma unroll
    for (int fi = 0; fi < 4; ++fi) {
      bf16x8 kf[4];
#pragma unroll
      for (int mt = 0; mt < 4; ++mt)
        kf[mt] = *reinterpret_cast<const bf16x8*>(
            &Kcur[(mt * 16 + c) * 128 + (((fi * 4 + g) ^ c) << 3)]);
      __builtin_amdgcn_s_setprio(1);
#pragma unroll
      for (int mt = 0; mt < 4; ++mt) {
        s[0][mt] = __builtin_amdgcn_mfma_f32_16x16x32_bf16(kf[mt], qf[0][fi], s[0][mt], 0, 0, 0);
        s[1][mt] = __builtin_amdgcn_mfma_f32_16x16x32_bf16(kf[mt], qf[1][fi], s[1][mt], 0, 0, 0);
      }
      __builtin_amdgcn_s_setprio(0);
    }

    uint32_t pku[2][4][2];
#pragma unroll
    for (int qt = 0; qt < 2; ++qt) {
      float ls = 0.f;
#pragma unroll
      for (int mt = 0; mt < 4; ++mt) {
        float p0 = EXP2F(s[qt][mt][0]);
        float p1 = EXP2F(s[qt][mt][1]);
        float p2 = EXP2F(s[qt][mt][2]);
        float p3 = EXP2F(s[qt][mt][3]);
        ls += (p0 + p1) + (p2 + p3);
        pku[qt][mt][0] = pack_trunc(p0, p1);
        pku[qt][mt][1] = pack_trunc(p2, p3);
      }
      lsum[qt] += ls;
    }

    union u32x4_bf { uint32_t u[4]; bf16x8 v; };
    u32x4_bf pf[2][2];
#pragma unroll
    for (int qt = 0; qt < 2; ++qt) {
      pf[qt][0].u[0] = pku[qt][0][0]; pf[qt][0].u[1] = pku[qt][0][1];
      pf[qt][0].u[2] = pku[qt][1][0]; pf[qt][0].u[3] = pku[qt][1][1];
      pf[qt][1].u[0] = pku[qt][2][0]; pf[qt][1].u[1] = pku[qt][2][1];
      pf[qt][1].u[2] = pku[qt][3][0]; pf[qt][1].u[3] = pku[qt][3][1];
    }
#pragma unroll
    for (int at = 0; at < 4; ++at) {
      int arow = at * 16 + c;
      bf16x8 vf0 = *reinterpret_cast<const bf16x8*>(
          &Vcur[arow * 64 + ((g ^ (arow & 7)) << 3)]);
      bf16x8 vf1 = *reinterpret_cast<const bf16x8*>(
          &Vcur[arow * 64 + (((4 + g) ^ (arow & 7)) << 3)]);
      __builtin_amdgcn_s_setprio(1);
#pragma unroll
      for (int qt = 0; qt < 2; ++qt) {
        o[qt][at] = __builtin_amdgcn_mfma_f32_16x16x32_bf16(pf[qt][0].v, vf0, o[qt][at], 0, 0, 0);
        o[qt][at] = __builtin_amdgcn_mfma_f32_16x16x32_bf16(pf[qt][1].v, vf1, o[qt][at], 0, 0, 0);
      }
      __builtin_amdgcn_s_setprio(0);
    }
    __syncthreads();
  }

  // ---- coalesced epilogue via LDS tile [128 l][64 col] (reuses alds[0..8191]) ----
  int b = bh >> 3, h = bh & 7;
#pragma unroll
  for (int qt = 0; qt < 2; ++qt) {
    lsum[qt] += __shfl_xor(lsum[qt], 16);
    lsum[qt] += __shfl_xor(lsum[qt], 32);
    float rinv[4];
#pragma unroll
    for (int r = 0; r < 4; ++r) rinv[r] = 1.0f / __shfl(lsum[qt], g * 4 + r);
#pragma unroll
    for (int at = 0; at < 4; ++at) {
      int col = at * 16 + c;
      int colch = col >> 3, cw = col & 7;
#pragma unroll
      for (int r = 0; r < 4; ++r) {
        int l_loc = w * 32 + qt * 16 + g * 4 + r;
        alds[l_loc * 64 + ((colch ^ (l_loc & 7)) << 3) + cw] = f2bfu(o[qt][at][r] * rinv[r]);
      }
    }
  }
  __syncthreads();
#pragma unroll
  for (int jj = 0; jj < 4; ++jj) {
    int q = t + jj * 256;
    int l_loc = q >> 3, ch = q & 7;
    uint4 d = *reinterpret_cast<const uint4*>(
        &alds[l_loc * 64 + ((ch ^ (l_loc & 7)) << 3)]);
    *reinterpret_cast<uint4*>(
        &ctxb[(size_t)(b * 2048 + qb * 128 + l_loc) * 512 + h * 64 + ch * 8]) = d;
  }
}

// ---- K3: out-proj + bias + residual -> d_out f32, coalesced epilogue via LDS ----
__global__ __launch_bounds__(256) void k_oproj(
    const unsigned short* __restrict__ ctxb, const unsigned short* __restrict__ wt,
    const float* __restrict__ bo, const float* __restrict__ resid,
    float* __restrict__ out) {
  __shared__ __align__(16) unsigned short oplds[8192];  // Al[4096] | Bl[4096]
  int bid = blockIdx.x;
  int rb = bid >> 3, cb = bid & 7;
  const unsigned short* Ag = ctxb + (size_t)rb * 64 * 512;
  const unsigned short* Wg = wt + (size_t)5 * 262144 + (size_t)cb * 64 * 512;
  f32x4 acc[4];
#pragma unroll
  for (int i = 0; i < 4; ++i) acc[i] = f32x4{0.f, 0.f, 0.f, 0.f};
  gemm_core(Ag, Wg, oplds, oplds + 4096, acc);
  int t = threadIdx.x;
  int lane = t & 63, w = t >> 6, g = lane >> 4, c = lane & 15;
  __syncthreads();  // compute done; reuse LDS as [64 l][64 n] f32 tile
  float* fl = reinterpret_cast<float*>(oplds);
#pragma unroll
  for (int ct = 0; ct < 4; ++ct) {
    int col = ct * 16 + c;
    int colch = col >> 2, cw = col & 3;
    float bv = bo[cb * 64 + col];
#pragma unroll
    for (int r = 0; r < 4; ++r) {
      int l_loc = w * 16 + g * 4 + r;
      fl[l_loc * 64 + ((colch ^ (l_loc & 15)) << 2) + cw] = acc[ct][r] + bv;
    }
  }
  __syncthreads();
#pragma unroll
  for (int j = 0; j < 4; ++j) {
    int q = t + j * 256;
    int l_loc = q >> 4, ch = q & 15;
    f32x4 d = *reinterpret_cast<const f32x4*>(
        &fl[l_loc * 64 + ((ch ^ (l_loc & 15)) << 2)]);
    size_t di = (size_t)(rb * 64 + l_loc) * 512 + cb * 64 + ch * 4;
    f32x4 rs = *reinterpret_cast<const f32x4*>(&resid[di]);
    *reinterpret_cast<f32x4*>(&out[di]) = d + rs;
  }
}

// ---------------- K4: in-place LayerNorm over D=512, one row per wave ----------------
__global__ __launch_bounds__(256) void k_ln(float* __restrict__ out,
                                            const float* __restrict__ gam,
                                            const float* __restrict__ bet) {
  int row = blockIdx.x * 4 + (threadIdx.x >> 6);
  int lane = threadIdx.x & 63;
  float* x = out + (size_t)row * 512 + lane * 8;
  float4 v0 = reinterpret_cast<const float4*>(x)[0];
  float4 v1 = reinterpret_cast<const float4*>(x)[1];
  float s = v0.x + v0.y + v0.z + v0.w + v1.x + v1.y + v1.z + v1.w;
  float q = v0.x * v0.x + v0.y * v0.y + v0.z * v0.z + v0.w * v0.w +
            v1.x * v1.x + v1.y * v1.y + v1.z * v1.z + v1.w * v1.w;
#pragma unroll
  for (int d = 1; d < 64; d <<= 1) {
    s += __shfl_xor(s, d);
    q += __shfl_xor(q, d);
  }
  float mu = s * (1.0f / 512.0f);
  float var = q * (1.0f / 512.0f) - mu * mu;
  float rstd = rsqrtf(var + 1e-5f);
  float4 g0 = reinterpret_cast<const float4*>(gam + lane * 8)[0];
  float4 g1 = reinterpret_cast<const float4*>(gam + lane * 8)[1];
  float4 b0 = reinterpret_cast<const float4*>(bet + lane * 8)[0];
  float4 b1 = reinterpret_cast<const float4*>(bet + lane * 8)[1];
  v0.x = (v0.x - mu) * rstd * g0.x + b0.x;
  v0.y = (v0.y - mu) * rstd * g0.y + b0.y;
  v0.z = (v0.z - mu) * rstd * g0.z + b0.z;
  v0.w = (v0.w - mu) * rstd * g0.w + b0.w;
  v1.x = (v1.x - mu) * rstd * g1.x + b1.x;
  v1.y = (v1.y - mu) * rstd * g1.y + b1.y;
  v1.z = (v1.z - mu) * rstd * g1.z + b1.z;
  v1.w = (v1.w - mu) * rstd * g1.w + b1.w;
  reinterpret_cast<float4*>(x)[0] = v0;
  reinterpret_cast<float4*>(x)[1] = v1;
}

extern "C" void kernel_launch(void* const* d_in, const int* in_sizes, int n_in,
                              void* d_out, int out_size, void* d_ws, size_t ws_size,
                              hipStream_t stream) {
  const float* Qd  = (const float*)d_in[0];
  const float* Qt  = (const float*)d_in[1];
  const float* Kd  = (const float*)d_in[2];
  const float* Kt  = (const float*)d_in[3];
  const float* Vt  = (const float*)d_in[4];
  const float* Wqd = (const float*)d_in[5];
  const float* bqd = (const float*)d_in[6];
  const float* Wqt = (const float*)d_in[7];
  const float* bqt = (const float*)d_in[8];
  const float* Wkd = (const float*)d_in[9];
  const float* bkd = (const float*)d_in[10];
  const float* Wkt = (const float*)d_in[11];
  const float* bkt = (const float*)d_in[12];
  const float* Wvt = (const float*)d_in[13];
  const float* bvt = (const float*)d_in[14];
  const float* Wo  = (const float*)d_in[15];
  const float* bo  = (const float*)d_in[16];
  const float* lng = (const float*)d_in[17];
  const float* lnb = (const float*)d_in[18];

  char* ws = (char*)d_ws;
  unsigned short* wt   = (unsigned short*)(ws);
  unsigned short* qws  = (unsigned short*)(ws + 3145728);
  unsigned short* kws  = (unsigned short*)(ws + 19922944);
  unsigned short* vws  = (unsigned short*)(ws + 36700160);
  unsigned short* ctxb = (unsigned short*)(ws + 45088768);
  float* out = (float*)d_out;

  k_prep_w<<<384, 256, 0, stream>>>(Wqd, Wqt, Wkd, Wkt, Wvt, Wo, wt);
  k_proj2<<<1280, 512, 0, stream>>>(Qd, Qt, Kd, Kt, Vt, wt,
                                    bqd, bqt, bkd, bkt, bvt, qws, kws, vws);
  k_attn<<<512, 256, 0, stream>>>(qws, kws, vws, ctxb);
  k_oproj<<<1024, 256, 0, stream>>>(ctxb, wt, bo, Qd, out);
  k_ln<<<2048, 256, 0, stream>>>(out, lng, lnb);
}

// Round 21
// 122.399 us; speedup vs baseline: 1.3196x; 1.0413x over previous
//
#include <hip/hip_runtime.h>
#include <hip/hip_bf16.h>
#include <stdint.h>

// MixAttention: B=4, L=2048, D=512, H=8, A=64
// ws layout (bytes):
//  wt   @ 0        : 6*512*512*2   = 3145728   (W^T bf16, [mat][out][in])
//  qws  @ 3145728  : 32*2048*128*2 = 16777216  (Q' = [qd|qt]*0.125*log2e, [bh][l][128])
//  kws  @ 19922944 : 16777216                  (K' = [kd|kt], [bh][l][128])
//  vws  @ 36700160 : 32*64*2048*2  = 8388608   (V^T, [bh][a][l'], l' pi-permuted in 64-blocks)
//  ctxb @ 45088768 : 8192*512*2    = 8388608   (attn out, [row][512])

using f32x4  = __attribute__((ext_vector_type(4))) float;
using bf16x8 = __attribute__((ext_vector_type(8))) short;

typedef __attribute__((address_space(1))) const uint32_t g_u32;
typedef __attribute__((address_space(3))) uint32_t l_u32;

#if __has_builtin(__builtin_amdgcn_exp2f)
#define EXP2F __builtin_amdgcn_exp2f
#else
#define EXP2F exp2f
#endif
#define QSCALE 0.1803368801111204f  /* 0.125 * log2(e): scores in log2 units */

__device__ __forceinline__ void glds16(const void* g, void* l) {
  __builtin_amdgcn_global_load_lds((g_u32*)g, (l_u32*)l, 16, 0, 0);
}

__device__ __forceinline__ unsigned short f2bfu(float f) {
  __hip_bfloat16 h = __float2bfloat16(f);
  union { __hip_bfloat16 h; unsigned short u; } v;
  v.h = h;
  return v.u;
}

// pack two non-negative finite floats to 2xbf16 by truncation (1 v_perm_b32)
__device__ __forceinline__ uint32_t pack_trunc(float lo, float hi) {
  union { float f; uint32_t u; } a, b;
  a.f = lo; b.f = hi;
  return __builtin_amdgcn_perm(b.u, a.u, 0x07060302u);
}

// ---------------- K0a: W [512 in][512 out] f32 -> W^T [out][in] bf16 ----------------
__global__ __launch_bounds__(256) void k_prep_w(
    const float* __restrict__ w0, const float* __restrict__ w1,
    const float* __restrict__ w2, const float* __restrict__ w3,
    const float* __restrict__ w4, const float* __restrict__ w5,
    unsigned short* __restrict__ wt) {
  __shared__ float tile[64][68];
  const float* wsrc[6] = {w0, w1, w2, w3, w4, w5};
  int bid = blockIdx.x;
  int mat = bid >> 6, tid = bid & 63;
  int k0 = (tid >> 3) << 6, c0 = (tid & 7) << 6;
  const float* w = wsrc[mat];
  int t = threadIdx.x;
  {
    int r = t >> 2, cq = (t & 3) << 4;
    const float4* src = reinterpret_cast<const float4*>(w + (size_t)(k0 + r) * 512 + c0 + cq);
#pragma unroll
    for (int j = 0; j < 4; ++j) {
      float4 v = src[j];
      tile[r][cq + j * 4 + 0] = v.x;
      tile[r][cq + j * 4 + 1] = v.y;
      tile[r][cq + j * 4 + 2] = v.z;
      tile[r][cq + j * 4 + 3] = v.w;
    }
  }
  __syncthreads();
  {
    int cc = t >> 2, kq = (t & 3) << 4;
    union { unsigned short u[16]; uint4 v[2]; } p;
#pragma unroll
    for (int j = 0; j < 16; ++j) p.u[j] = f2bfu(tile[kq + j][cc]);
    unsigned short* dst = wt + (size_t)mat * 262144 + (size_t)(c0 + cc) * 512 + k0 + kq;
    *reinterpret_cast<uint4*>(dst)     = p.v[0];
    *reinterpret_cast<uint4*>(dst + 8) = p.v[1];
  }
}

// ---- K1: 5 projections, 128x128 tile, 8 waves; A reg-prefetch + B glds16 dbuf.
//      Coalesced epilogue via LDS round-trip. (R20 verbatim)
__global__ __launch_bounds__(512) void k_proj2(
    const float* __restrict__ x0, const float* __restrict__ x1,
    const float* __restrict__ x2, const float* __restrict__ x3,
    const float* __restrict__ x4,
    const unsigned short* __restrict__ wt,
    const float* __restrict__ b0, const float* __restrict__ b1,
    const float* __restrict__ b2, const float* __restrict__ b3,
    const float* __restrict__ b4,
    unsigned short* __restrict__ qws, unsigned short* __restrict__ kws,
    unsigned short* __restrict__ vws) {
  __shared__ __align__(16) unsigned short plds[24576];  // Abuf[8192] | Bbuf0[8192] | Bbuf1[8192]
  int bid = blockIdx.x;
  int proj = bid >> 8, rem = bid & 255;
  int cb = rem >> 6, rb = rem & 63;
  const float* xs[5] = {x0, x1, x2, x3, x4};
  const float* Ag = xs[proj] + (size_t)rb * 128 * 512;
  const unsigned short* Wg = wt + (size_t)proj * 262144 + (size_t)cb * 128 * 512;
  int t = threadIdx.x;
  int lane = t & 63, w = t >> 6, wr = w >> 2, wc = w & 3, g = lane >> 4, c = lane & 15;
  f32x4 acc[4][2];
#pragma unroll
  for (int i = 0; i < 4; ++i)
#pragma unroll
    for (int j = 0; j < 2; ++j) acc[i][j] = f32x4{0.f, 0.f, 0.f, 0.f};

  int srow[2], sch[2];
#pragma unroll
  for (int j = 0; j < 2; ++j) {
    int q = t + j * 512;
    srow[j] = q >> 3;
    sch[j] = q & 7;
  }
  float4 pa[2], pb[2];
#pragma unroll
  for (int j = 0; j < 2; ++j) {
    const float* src = Ag + (size_t)srow[j] * 512 + sch[j] * 8;
    pa[j] = *reinterpret_cast<const float4*>(src);
    pb[j] = *reinterpret_cast<const float4*>(src + 4);
  }
#pragma unroll
  for (int j = 0; j < 2; ++j) {
    int cid = t + j * 512;
    int row = cid >> 3, ch = cid & 7;
    glds16(Wg + (size_t)row * 512 + ((ch ^ (row & 7)) << 3),
           plds + 8192 + cid * 8);
  }

#pragma unroll 1
  for (int it = 0; it < 8; ++it) {
    int cur = it & 1;
    unsigned short* Bcur = plds + 8192 + cur * 8192;
    unsigned short* Bnxt = plds + 8192 + (cur ^ 1) * 8192;
    __syncthreads();  // drains A-regs + B(it) glds16 (issued a full compute-phase ago)
#pragma unroll
    for (int j = 0; j < 2; ++j) {
      union { unsigned short u[8]; uint4 v; } p;
      p.u[0] = f2bfu(pa[j].x); p.u[1] = f2bfu(pa[j].y);
      p.u[2] = f2bfu(pa[j].z); p.u[3] = f2bfu(pa[j].w);
      p.u[4] = f2bfu(pb[j].x); p.u[5] = f2bfu(pb[j].y);
      p.u[6] = f2bfu(pb[j].z); p.u[7] = f2bfu(pb[j].w);
      *reinterpret_cast<uint4*>(&plds[srow[j] * 64 + ((sch[j] ^ (srow[j] & 7)) << 3)]) = p.v;
    }
    __syncthreads();  // drains only lgkm (A ds_write) -- cheap
    if (it < 7) {
#pragma unroll
      for (int j = 0; j < 2; ++j) {
        const float* src = Ag + (size_t)srow[j] * 512 + (it + 1) * 64 + sch[j] * 8;
        pa[j] = *reinterpret_cast<const float4*>(src);
        pb[j] = *reinterpret_cast<const float4*>(src + 4);
      }
#pragma unroll
      for (int j = 0; j < 2; ++j) {
        int cid = t + j * 512;
        int row = cid >> 3, ch = cid & 7;
        glds16(Wg + (size_t)row * 512 + (it + 1) * 64 + ((ch ^ (row & 7)) << 3),
               Bnxt + cid * 8);
      }
    }
#pragma unroll
    for (int fi = 0; fi < 2; ++fi) {
      bf16x8 af[4], bfr[2];
#pragma unroll
      for (int mi = 0; mi < 4; ++mi) {
        int arow = wr * 64 + mi * 16 + c;
        af[mi] = *reinterpret_cast<const bf16x8*>(
            &plds[arow * 64 + (((fi * 4 + g) ^ (arow & 7)) << 3)]);
      }
#pragma unroll
      for (int ni = 0; ni < 2; ++ni) {
        int brow = wc * 32 + ni * 16 + c;
        bfr[ni] = *reinterpret_cast<const bf16x8*>(
            &Bcur[brow * 64 + (((fi * 4 + g) ^ (brow & 7)) << 3)]);
      }
      __builtin_amdgcn_s_setprio(1);
#pragma unroll
      for (int mi = 0; mi < 4; ++mi)
#pragma unroll
        for (int ni = 0; ni < 2; ++ni)
          acc[mi][ni] = __builtin_amdgcn_mfma_f32_16x16x32_bf16(af[mi], bfr[ni], acc[mi][ni], 0, 0, 0);
      __builtin_amdgcn_s_setprio(0);
    }
  }

  // ---- coalesced epilogue via LDS (plds[0..16383] = 32KB tile) ----
  const float* bias_arr[5] = {b0, b1, b2, b3, b4};
  const float* bias = bias_arr[proj];
  float scale = (proj < 2) ? QSCALE : 1.0f;
  int bglob = rb >> 4;            // batch index (rows rb*128 span one batch)
  int lbase = (rb & 15) * 128;    // l offset within [0,2048)
  __syncthreads();                // compute done; safe to reuse staging LDS
  if (proj < 4) {
    unsigned short* qkdst = (proj < 2) ? qws : kws;
    int half = (proj & 1) ? 64 : 0;
#pragma unroll
    for (int ni = 0; ni < 2; ++ni) {
      int col = wc * 32 + ni * 16 + c;
      int colch = col >> 3, cw = col & 7;
      float bv = bias[cb * 128 + col];
#pragma unroll
      for (int mi = 0; mi < 4; ++mi)
#pragma unroll
        for (int rr = 0; rr < 4; ++rr) {
          int l_loc = wr * 64 + mi * 16 + g * 4 + rr;
          float v = (acc[mi][ni][rr] + bv) * scale;
          plds[l_loc * 128 + ((colch ^ (l_loc & 15)) << 3) + cw] = f2bfu(v);
        }
    }
    __syncthreads();
#pragma unroll
    for (int j = 0; j < 4; ++j) {
      int q = t + j * 512;
      int l_loc = q >> 4, ch = q & 15;
      uint4 d = *reinterpret_cast<const uint4*>(
          &plds[l_loc * 128 + ((ch ^ (l_loc & 15)) << 3)]);
      int n0 = cb * 128 + ch * 8;
      int h = n0 >> 6, a0 = n0 & 63;
      *reinterpret_cast<uint4*>(
          &qkdst[((size_t)(bglob * 8 + h) * 2048 + lbase + l_loc) * 128 + half + a0]) = d;
    }
  } else {
#pragma unroll
    for (int ni = 0; ni < 2; ++ni) {
      int n_loc = wc * 32 + ni * 16 + c;
      float bv = bias[cb * 128 + n_loc];
#pragma unroll
      for (int mi = 0; mi < 4; ++mi) {
        int P = ((mi & 2) << 4) | (g << 3) | ((mi & 1) << 2);  // perm base; rr = low 2 bits
        int lp = wr * 64 + P;
        int c16 = lp >> 3, h8 = (lp >> 2) & 1;
        uint2 pk;
        pk.x = (uint32_t)f2bfu(acc[mi][ni][0] + bv) |
               ((uint32_t)f2bfu(acc[mi][ni][1] + bv) << 16);
        pk.y = (uint32_t)f2bfu(acc[mi][ni][2] + bv) |
               ((uint32_t)f2bfu(acc[mi][ni][3] + bv) << 16);
        *reinterpret_cast<uint2*>(
            &plds[(n_loc * 16 + (c16 ^ (n_loc & 15))) * 8 + h8 * 4]) = pk;
      }
    }
    __syncthreads();
#pragma unroll
    for (int j = 0; j < 4; ++j) {
      int q = t + j * 512;
      int n_loc = q & 127, c16 = q >> 7;
      uint4 d = *reinterpret_cast<const uint4*>(
          &plds[(n_loc * 16 + (c16 ^ (n_loc & 15))) * 8]);
      int n0 = cb * 128 + n_loc;
      int h = n0 >> 6, a = n0 & 63;
      *reinterpret_cast<uint4*>(
          &vws[((size_t)(bglob * 8 + h) * 64 + a) * 2048 + lbase + c16 * 8]) = d;
    }
  }
}

// ---------------- shared GEMM core: 64x64 tile (k_oproj) ----------------
__device__ __forceinline__ void gemm_core(
    const unsigned short* Ag, const unsigned short* Wg,
    unsigned short* Al, unsigned short* Bl, f32x4 acc[4]) {
  int t = threadIdx.x;
  int lane = t & 63, w = t >> 6, g = lane >> 4, c = lane & 15;
#pragma unroll 1
  for (int it = 0; it < 8; ++it) {
    __syncthreads();
#pragma unroll
    for (int j = 0; j < 2; ++j) {
      int cid = t + j * 256;
      int row = cid >> 3, ch = cid & 7;
      glds16(Ag + (size_t)row * 512 + it * 64 + ((ch ^ (row & 7)) << 3), Al + cid * 8);
      glds16(Wg + (size_t)row * 512 + it * 64 + ((ch ^ (row & 7)) << 3), Bl + cid * 8);
    }
    __syncthreads();
#pragma unroll
    for (int fi = 0; fi < 2; ++fi) {
      int arow = w * 16 + c;
      bf16x8 af = *reinterpret_cast<const bf16x8*>(
          Al + arow * 64 + (((fi * 4 + g) ^ (arow & 7)) << 3));
#pragma unroll
      for (int ct = 0; ct < 4; ++ct) {
        int brow = ct * 16 + c;
        bf16x8 bf = *reinterpret_cast<const bf16x8*>(
            Bl + brow * 64 + (((fi * 4 + g) ^ (brow & 7)) << 3));
        acc[ct] = __builtin_amdgcn_mfma_f32_16x16x32_bf16(af, bf, acc[ct], 0, 0, 0);
      }
    }
  }
}

// ---- K2: flash attention, 8 waves x 256 q-rows per block (staging shared by 2x waves),
//      static-max softmax, P in regs, b128 V reads (pi-permuted), coalesced epilogue ----
__global__ __launch_bounds__(512) void k_attn(
    const unsigned short* __restrict__ qws, const unsigned short* __restrict__ kws,
    const unsigned short* __restrict__ vws, unsigned short* __restrict__ ctxb) {
  __shared__ __align__(16) unsigned short alds[32768];  // Kb0[8192]|Kb1[8192]|Vb0[4096]|Vb1[4096]|epi
  int orig = blockIdx.x;
  // 256 blocks: XCD x owns bh in [x*4, x*4+4); qb in [0,8) of 256 rows
  int xcd = orig & 7, j = orig >> 3;
  int bh = xcd * 4 + (j >> 3), qb = j & 7;
  int t = threadIdx.x;
  int w = t >> 6, lane = t & 63, g = lane >> 4, c = lane & 15;

  const unsigned short* Kg = kws + (size_t)bh * 2048 * 128;
  const unsigned short* Vg = vws + (size_t)bh * 64 * 2048;

  bf16x8 qf[2][4];
#pragma unroll
  for (int qt = 0; qt < 2; ++qt) {
    const unsigned short* Qg =
        qws + ((size_t)bh * 2048 + qb * 256 + w * 32 + qt * 16 + c) * 128;
#pragma unroll
    for (int fi = 0; fi < 4; ++fi)
      qf[qt][fi] = *reinterpret_cast<const bf16x8*>(Qg + fi * 32 + g * 8);
  }

  f32x4 o[2][4];
#pragma unroll
  for (int qt = 0; qt < 2; ++qt)
#pragma unroll
    for (int at = 0; at < 4; ++at) o[qt][at] = f32x4{0.f, 0.f, 0.f, 0.f};
  float lsum[2] = {0.f, 0.f};

  // prologue: stage tile 0 (K: 1024 cells over 512 thr = 2 each; V: 512 cells = 1 each)
#pragma unroll
  for (int jj = 0; jj < 2; ++jj) {
    int cid = t + jj * 512;
    int row = cid >> 4, ch = cid & 15;
    glds16(Kg + (size_t)row * 128 + ((ch ^ (row & 15)) << 3), alds + cid * 8);
  }
  {
    int a = t >> 3, ch = t & 7;
    glds16(Vg + (size_t)a * 2048 + ((ch ^ (a & 7)) << 3), alds + 16384 + t * 8);
  }
  __syncthreads();

#pragma unroll 1
  for (int it = 0; it < 32; ++it) {
    int cur = it & 1;
    unsigned short* Kcur = alds + cur * 8192;
    unsigned short* Vcur = alds + 16384 + cur * 4096;
    if (it < 31) {
      unsigned short* Knxt = alds + (cur ^ 1) * 8192;
      unsigned short* Vnxt = alds + 16384 + (cur ^ 1) * 4096;
#pragma unroll
      for (int jj = 0; jj < 2; ++jj) {
        int cid = t + jj * 512;
        int row = cid >> 4, ch = cid & 15;
        glds16(Kg + ((size_t)(it + 1) * 64 + row) * 128 + ((ch ^ (row & 15)) << 3),
               Knxt + cid * 8);
      }
      {
        int a = t >> 3, ch = t & 7;
        glds16(Vg + (size_t)a * 2048 + (it + 1) * 64 + ((ch ^ (a & 7)) << 3),
               Vnxt + t * 8);
      }
    }

    f32x4 s[2][4];
#pragma unroll
    for (int qt = 0; qt < 2; ++qt)
#pragma unroll
      for (int mt = 0; mt < 4; ++mt) s[qt][mt] = f32x4{0.f, 0.f, 0.f, 0.f};
#pragma unroll
    for (int fi = 0; fi < 4; ++fi) {
      bf16x8 kf[4];
#pragma unroll
      for (int mt = 0; mt < 4; ++mt)
        kf[mt] = *reinterpret_cast<const bf16x8*>(
            &Kcur[(mt * 16 + c) * 128 + (((fi * 4 + g) ^ c) << 3)]);
      __builtin_amdgcn_s_setprio(1);
#pragma unroll
      for (int mt = 0; mt < 4; ++mt) {
        s[0][mt] = __builtin_amdgcn_mfma_f32_16x16x32_bf16(kf[mt], qf[0][fi], s[0][mt], 0, 0, 0);
        s[1][mt] = __builtin_amdgcn_mfma_f32_16x16x32_bf16(kf[mt], qf[1][fi], s[1][mt], 0, 0, 0);
      }
      __builtin_amdgcn_s_setprio(0);
    }

    uint32_t pku[2][4][2];
#pragma unroll
    for (int qt = 0; qt < 2; ++qt) {
      float ls = 0.f;
#pragma unroll
      for (int mt = 0; mt < 4; ++mt) {
        float p0 = EXP2F(s[qt][mt][0]);
        float p1 = EXP2F(s[qt][mt][1]);
        float p2 = EXP2F(s[qt][mt][2]);
        float p3 = EXP2F(s[qt][mt][3]);
        ls += (p0 + p1) + (p2 + p3);
        pku[qt][mt][0] = pack_trunc(p0, p1);
        pku[qt][mt][1] = pack_trunc(p2, p3);
      }
      lsum[qt] += ls;
    }

    union u32x4_bf { uint32_t u[4]; bf16x8 v; };
    u32x4_bf pf[2][2];
#pragma unroll
    for (int qt = 0; qt < 2; ++qt) {
      pf[qt][0].u[0] = pku[qt][0][0]; pf[qt][0].u[1] = pku[qt][0][1];
      pf[qt][0].u[2] = pku[qt][1][0]; pf[qt][0].u[3] = pku[qt][1][1];
      pf[qt][1].u[0] = pku[qt][2][0]; pf[qt][1].u[1] = pku[qt][2][1];
      pf[qt][1].u[2] = pku[qt][3][0]; pf[qt][1].u[3] = pku[qt][3][1];
    }
#pragma unroll
    for (int at = 0; at < 4; ++at) {
      int arow = at * 16 + c;
      bf16x8 vf0 = *reinterpret_cast<const bf16x8*>(
          &Vcur[arow * 64 + ((g ^ (arow & 7)) << 3)]);
      bf16x8 vf1 = *reinterpret_cast<const bf16x8*>(
          &Vcur[arow * 64 + (((4 + g) ^ (arow & 7)) << 3)]);
      __builtin_amdgcn_s_setprio(1);
#pragma unroll
      for (int qt = 0; qt < 2; ++qt) {
        o[qt][at] = __builtin_amdgcn_mfma_f32_16x16x32_bf16(pf[qt][0].v, vf0, o[qt][at], 0, 0, 0);
        o[qt][at] = __builtin_amdgcn_mfma_f32_16x16x32_bf16(pf[qt][1].v, vf1, o[qt][at], 0, 0, 0);
      }
      __builtin_amdgcn_s_setprio(0);
    }
    __syncthreads();
  }

  // ---- coalesced epilogue via LDS tile [256 l][64 col] (reuses alds, 32KB) ----
  int b = bh >> 3, h = bh & 7;
#pragma unroll
  for (int qt = 0; qt < 2; ++qt) {
    lsum[qt] += __shfl_xor(lsum[qt], 16);
    lsum[qt] += __shfl_xor(lsum[qt], 32);
    float rinv[4];
#pragma unroll
    for (int r = 0; r < 4; ++r) rinv[r] = 1.0f / __shfl(lsum[qt], g * 4 + r);
#pragma unroll
    for (int at = 0; at < 4; ++at) {
      int col = at * 16 + c;
      int colch = col >> 3, cw = col & 7;
#pragma unroll
      for (int r = 0; r < 4; ++r) {
        int l_loc = w * 32 + qt * 16 + g * 4 + r;
        alds[l_loc * 64 + ((colch ^ (l_loc & 7)) << 3) + cw] = f2bfu(o[qt][at][r] * rinv[r]);
      }
    }
  }
  __syncthreads();
#pragma unroll
  for (int jj = 0; jj < 4; ++jj) {
    int q = t + jj * 512;
    int l_loc = q >> 3, ch = q & 7;
    uint4 d = *reinterpret_cast<const uint4*>(
        &alds[l_loc * 64 + ((ch ^ (l_loc & 7)) << 3)]);
    *reinterpret_cast<uint4*>(
        &ctxb[(size_t)(b * 2048 + qb * 256 + l_loc) * 512 + h * 64 + ch * 8]) = d;
  }
}

// ---- K3: out-proj + bias + residual -> d_out f32, coalesced epilogue via LDS ----
__global__ __launch_bounds__(256) void k_oproj(
    const unsigned short* __restrict__ ctxb, const unsigned short* __restrict__ wt,
    const float* __restrict__ bo, const float* __restrict__ resid,
    float* __restrict__ out) {
  __shared__ __align__(16) unsigned short oplds[8192];  // Al[4096] | Bl[4096]
  int bid = blockIdx.x;
  int rb = bid >> 3, cb = bid & 7;
  const unsigned short* Ag = ctxb + (size_t)rb * 64 * 512;
  const unsigned short* Wg = wt + (size_t)5 * 262144 + (size_t)cb * 64 * 512;
  f32x4 acc[4];
#pragma unroll
  for (int i = 0; i < 4; ++i) acc[i] = f32x4{0.f, 0.f, 0.f, 0.f};
  gemm_core(Ag, Wg, oplds, oplds + 4096, acc);
  int t = threadIdx.x;
  int lane = t & 63, w = t >> 6, g = lane >> 4, c = lane & 15;
  __syncthreads();  // compute done; reuse LDS as [64 l][64 n] f32 tile
  float* fl = reinterpret_cast<float*>(oplds);
#pragma unroll
  for (int ct = 0; ct < 4; ++ct) {
    int col = ct * 16 + c;
    int colch = col >> 2, cw = col & 3;
    float bv = bo[cb * 64 + col];
#pragma unroll
    for (int r = 0; r < 4; ++r) {
      int l_loc = w * 16 + g * 4 + r;
      fl[l_loc * 64 + ((colch ^ (l_loc & 15)) << 2) + cw] = acc[ct][r] + bv;
    }
  }
  __syncthreads();
#pragma unroll
  for (int j = 0; j < 4; ++j) {
    int q = t + j * 256;
    int l_loc = q >> 4, ch = q & 15;
    f32x4 d = *reinterpret_cast<const f32x4*>(
        &fl[l_loc * 64 + ((ch ^ (l_loc & 15)) << 2)]);
    size_t di = (size_t)(rb * 64 + l_loc) * 512 + cb * 64 + ch * 4;
    f32x4 rs = *reinterpret_cast<const f32x4*>(&resid[di]);
    *reinterpret_cast<f32x4*>(&out[di]) = d + rs;
  }
}

// ---------------- K4: in-place LayerNorm over D=512, one row per wave ----------------
__global__ __launch_bounds__(256) void k_ln(float* __restrict__ out,
                                            const float* __restrict__ gam,
                                            const float* __restrict__ bet) {
  int row = blockIdx.x * 4 + (threadIdx.x >> 6);
  int lane = threadIdx.x & 63;
  float* x = out + (size_t)row * 512 + lane * 8;
  float4 v0 = reinterpret_cast<const float4*>(x)[0];
  float4 v1 = reinterpret_cast<const float4*>(x)[1];
  float s = v0.x + v0.y + v0.z + v0.w + v1.x + v1.y + v1.z + v1.w;
  float q = v0.x * v0.x + v0.y * v0.y + v0.z * v0.z + v0.w * v0.w +
            v1.x * v1.x + v1.y * v1.y + v1.z * v1.z + v1.w * v1.w;
#pragma unroll
  for (int d = 1; d < 64; d <<= 1) {
    s += __shfl_xor(s, d);
    q += __shfl_xor(q, d);
  }
  float mu = s * (1.0f / 512.0f);
  float var = q * (1.0f / 512.0f) - mu * mu;
  float rstd = rsqrtf(var + 1e-5f);
  float4 g0 = reinterpret_cast<const float4*>(gam + lane * 8)[0];
  float4 g1 = reinterpret_cast<const float4*>(gam + lane * 8)[1];
  float4 b0 = reinterpret_cast<const float4*>(bet + lane * 8)[0];
  float4 b1 = reinterpret_cast<const float4*>(bet + lane * 8)[1];
  v0.x = (v0.x - mu) * rstd * g0.x + b0.x;
  v0.y = (v0.y - mu) * rstd * g0.y + b0.y;
  v0.z = (v0.z - mu) * rstd * g0.z + b0.z;
  v0.w = (v0.w - mu) * rstd * g0.w + b0.w;
  v1.x = (v1.x - mu) * rstd * g1.x + b1.x;
  v1.y = (v1.y - mu) * rstd * g1.y + b1.y;
  v1.z = (v1.z - mu) * rstd * g1.z + b1.z;
  v1.w = (v1.w - mu) * rstd * g1.w + b1.w;
  reinterpret_cast<float4*>(x)[0] = v0;
  reinterpret_cast<float4*>(x)[1] = v1;
}

extern "C" void kernel_launch(void* const* d_in, const int* in_sizes, int n_in,
                              void* d_out, int out_size, void* d_ws, size_t ws_size,
                              hipStream_t stream) {
  const float* Qd  = (const float*)d_in[0];
  const float* Qt  = (const float*)d_in[1];
  const float* Kd  = (const float*)d_in[2];
  const float* Kt  = (const float*)d_in[3];
  const float* Vt  = (const float*)d_in[4];
  const float* Wqd = (const float*)d_in[5];
  const float* bqd = (const float*)d_in[6];
  const float* Wqt = (const float*)d_in[7];
  const float* bqt = (const float*)d_in[8];
  const float* Wkd = (const float*)d_in[9];
  const float* bkd = (const float*)d_in[10];
  const float* Wkt = (const float*)d_in[11];
  const float* bkt = (const float*)d_in[12];
  const float* Wvt = (const float*)d_in[13];
  const float* bvt = (const float*)d_in[14];
  const float* Wo  = (const float*)d_in[15];
  const float* bo  = (const float*)d_in[16];
  const float* lng = (const float*)d_in[17];
  const float* lnb = (const float*)d_in[18];

  char* ws = (char*)d_ws;
  unsigned short* wt   = (unsigned short*)(ws);
  unsigned short* qws  = (unsigned short*)(ws + 3145728);
  unsigned short* kws  = (unsigned short*)(ws + 19922944);
  unsigned short* vws  = (unsigned short*)(ws + 36700160);
  unsigned short* ctxb = (unsigned short*)(ws + 45088768);
  float* out = (float*)d_out;

  k_prep_w<<<384, 256, 0, stream>>>(Wqd, Wqt, Wkd, Wkt, Wvt, Wo, wt);
  k_proj2<<<1280, 512, 0, stream>>>(Qd, Qt, Kd, Kt, Vt, wt,
                                    bqd, bqt, bkd, bkt, bvt, qws, kws, vws);
  k_attn<<<256, 512, 0, stream>>>(qws, kws, vws, ctxb);
  k_oproj<<<1024, 256, 0, stream>>>(ctxb, wt, bo, Qd, out);
  k_ln<<<2048, 256, 0, stream>>>(out, lng, lnb);
}